// Round 1
// 102.996 us; speedup vs baseline: 1.0335x; 1.0335x over previous
//
#include <hip/hip_runtime.h>
#include <hip/hip_bf16.h>
#include <math.h>

// B=8, T=128, D=512. M = 1024 rows, N = 6*512 = 3072 concatenated outputs.
// Stage 0: split fp32 -> (hi,lo) bf16, packed per 32-K super-chunk
//          [32 hi | 32 lo]; float4-vectorized (4 elems/thread). UNCHANGED.
// Stage 1: R8 — small-shape latency fix. 64x64 tile -> 768 blocks
//          (3 independent blocks/CU = 3 separate barrier groups/SIMD),
//          triple-buffered LDS (3 x 16 KB), prefetch distance 2 with
//          RAW s_barrier + counted s_waitcnt vmcnt(4) (loads stay in
//          flight across barriers; no vmcnt(0) drain per stage).
//          lgkmcnt(0) before each barrier closes the buffer-reuse race.
// Stage 2: fused branches via degree-24 Taylor moments. UNCHANGED.

#define M_ROWS 1024
#define DIMD   512
#define NCOLS  3072
#define KPHYS  1024

typedef __attribute__((ext_vector_type(8))) short short8;
typedef __attribute__((ext_vector_type(4))) float f32x4;
typedef __attribute__((ext_vector_type(4))) unsigned short u16x4;

struct PtrArgs {
    const float* W[6];
    const float* b[6];
};

#define XN (M_ROWS * DIMD)
#define WN (NCOLS * DIMD)

__device__ __forceinline__ unsigned short bf16_rne(float v) {
    unsigned u = __float_as_uint(v);
    u = (u + 0x7FFFu + ((u >> 16) & 1u)) >> 16;
    return (unsigned short)u;
}

__device__ __constant__ float INVFACT[25] = {
    1.0f, 1.0f, 0.5f,
    1.6666666666666666e-01f, 4.1666666666666664e-02f, 8.3333333333333332e-03f,
    1.3888888888888889e-03f, 1.9841269841269841e-04f, 2.4801587301587302e-05f,
    2.7557319223985893e-06f, 2.7557319223985888e-07f, 2.5052108385441720e-08f,
    2.0876756987868100e-09f, 1.6059043836821613e-10f, 1.1470745597729725e-11f,
    7.6471637318198164e-13f, 4.7794773323873853e-14f, 2.8114572543455206e-15f,
    1.5619206968586225e-16f, 8.2206352466243295e-18f, 4.1103176233121648e-19f,
    1.9572941063391263e-20f, 8.8967913924505741e-22f, 3.8681701706306835e-23f,
    1.6117375710961184e-24f
};

// ---------------------------------------------------------------------------
// Stage 0: convert/split, float4-vectorized. UNCHANGED from R7.
// ---------------------------------------------------------------------------
__global__ __launch_bounds__(256) void convert_split(const float* __restrict__ x,
                                                     PtrArgs pa,
                                                     unsigned short* __restrict__ Aph,
                                                     unsigned short* __restrict__ Bph,
                                                     float* __restrict__ biasAll) {
    const int idx = blockIdx.x * 256 + threadIdx.x;   // vec4 index
    if (idx < NCOLS) {
        biasAll[idx] = pa.b[idx >> 9][idx & 511];
    }
    const int e4 = idx * 4;
    if (e4 < XN) {
        int m = e4 >> 9, k = e4 & 511;
        int s = k >> 5, p = k & 31;
        float4 v = *(const float4*)(x + e4);
        u16x4 hi, lo;
        hi.x = bf16_rne(v.x); lo.x = bf16_rne(v.x - __uint_as_float(((unsigned)hi.x) << 16));
        hi.y = bf16_rne(v.y); lo.y = bf16_rne(v.y - __uint_as_float(((unsigned)hi.y) << 16));
        hi.z = bf16_rne(v.z); lo.z = bf16_rne(v.z - __uint_as_float(((unsigned)hi.z) << 16));
        hi.w = bf16_rne(v.w); lo.w = bf16_rne(v.w - __uint_as_float(((unsigned)hi.w) << 16));
        *(u16x4*)&Aph[(size_t)m * KPHYS + s * 64 + p]      = hi;
        *(u16x4*)&Aph[(size_t)m * KPHYS + s * 64 + 32 + p] = lo;
    } else if (e4 < XN + WN) {
        int j = e4 - XN;
        int n = j >> 9, k = j & 511;
        int g = n >> 9, o = n & 511;
        int s = k >> 5, p = k & 31;
        float4 v = *(const float4*)(pa.W[g] + (size_t)o * DIMD + k);
        u16x4 hi, lo;
        hi.x = bf16_rne(v.x); lo.x = bf16_rne(v.x - __uint_as_float(((unsigned)hi.x) << 16));
        hi.y = bf16_rne(v.y); lo.y = bf16_rne(v.y - __uint_as_float(((unsigned)hi.y) << 16));
        hi.z = bf16_rne(v.z); lo.z = bf16_rne(v.z - __uint_as_float(((unsigned)hi.z) << 16));
        hi.w = bf16_rne(v.w); lo.w = bf16_rne(v.w - __uint_as_float(((unsigned)hi.w) << 16));
        *(u16x4*)&Bph[(size_t)n * KPHYS + s * 64 + p]      = hi;
        *(u16x4*)&Bph[(size_t)n * KPHYS + s * 64 + 32 + p] = lo;
    }
}

// ---------------------------------------------------------------------------
// Stage 1 (R8): 64x64 block tile, 4 waves as 2x2, wave tile 32x32 =
// 2x2 of 16x16x32 MFMAs x3 hi/lo terms. Triple-buffered LDS, prefetch
// distance 2, counted vmcnt. 768 blocks -> 3 blocks/CU (independent
// barrier groups). Chunk index XOR-swizzled with (row&7) on the GLOBAL
// address (layout identical to R7).
// ---------------------------------------------------------------------------
__global__ __launch_bounds__(256) void gemm_mfma(const unsigned short* __restrict__ A,
                                                 const unsigned short* __restrict__ B,
                                                 const float* __restrict__ biasAll,
                                                 float* __restrict__ Y) {
    __shared__ __align__(16) short As[3][64 * 64];    // 8 KB each
    __shared__ __align__(16) short Bs[3][64 * 64];    // 8 KB each

    const int tid  = threadIdx.x;
    const int m0   = blockIdx.y * 64;
    const int n0   = blockIdx.x * 64;
    const int lane = tid & 63;
    const int w    = tid >> 6;       // 0..3
    const int wm   = w & 1;
    const int wn   = w >> 1;         // 0..1
    const int l15  = lane & 15;
    const int quad = lane >> 4;

    f32x4 acc[2][2];
    #pragma unroll
    for (int i = 0; i < 2; ++i)
        #pragma unroll
        for (int j = 0; j < 2; ++j)
            acc[i][j] = (f32x4){0.f, 0.f, 0.f, 0.f};

    // One stage = one 32-logical-K super-chunk (64 phys shorts/row).
    // A: 64 rows x 8 chunks = 512 16B ops, 2/thread. B: same. 4 loads/thread.
    auto stage = [&](int s) {
        const int buf   = s % 3;
        const int kbase = s * 64;
        #pragma unroll
        for (int t = 0; t < 2; ++t) {
            int idx = t * 256 + tid;
            int r = idx >> 3, c = idx & 7;
            int cc = c ^ (r & 7);
            const unsigned short* ga = A + (size_t)(m0 + r) * KPHYS + kbase + cc * 8;
            __builtin_amdgcn_global_load_lds(
                (const __attribute__((address_space(1))) unsigned int*)ga,
                (__attribute__((address_space(3))) unsigned int*)&As[buf][idx * 8], 16, 0, 0);
        }
        #pragma unroll
        for (int t = 0; t < 2; ++t) {
            int idx = t * 256 + tid;
            int r = idx >> 3, c = idx & 7;
            int cc = c ^ (r & 7);
            const unsigned short* gb = B + (size_t)(n0 + r) * KPHYS + kbase + cc * 8;
            __builtin_amdgcn_global_load_lds(
                (const __attribute__((address_space(1))) unsigned int*)gb,
                (__attribute__((address_space(3))) unsigned int*)&Bs[buf][idx * 8], 16, 0, 0);
        }
    };

    stage(0);
    stage(1);

    #pragma unroll
    for (int it = 0; it < 16; ++it) {
        // Own frag reads executed before anyone may overwrite a buffer
        // one barrier later (buffer-reuse hazard).
        asm volatile("s_waitcnt lgkmcnt(0)" ::: "memory");
        // Counted wait: oldest 4 loads (= stage it) landed; stage it+1's
        // 4 loads stay in flight across the barrier.
        if (it < 15) asm volatile("s_waitcnt vmcnt(4)" ::: "memory");
        else         asm volatile("s_waitcnt vmcnt(0)" ::: "memory");
        __builtin_amdgcn_s_barrier();

        // Issue stage it+2 first: maximum flight time (~2 compute phases).
        if (it + 2 < 16) stage(it + 2);

        const int buf = it % 3;
        const short* as = As[buf];
        const short* bs = Bs[buf];
        short8 ah[2], al[2], bh[2], bl[2];
        #pragma unroll
        for (int mt = 0; mt < 2; ++mt) {
            int rA = wm * 32 + mt * 16 + l15;
            int ch = quad ^ (rA & 7);
            int cl = (4 + quad) ^ (rA & 7);
            ah[mt] = *(const short8*)&as[(rA * 8 + ch) * 8];
            al[mt] = *(const short8*)&as[(rA * 8 + cl) * 8];
        }
        #pragma unroll
        for (int nt = 0; nt < 2; ++nt) {
            int rB = wn * 32 + nt * 16 + l15;
            int ch = quad ^ (rB & 7);
            int cl = (4 + quad) ^ (rB & 7);
            bh[nt] = *(const short8*)&bs[(rB * 8 + ch) * 8];
            bl[nt] = *(const short8*)&bs[(rB * 8 + cl) * 8];
        }
        #pragma unroll
        for (int mt = 0; mt < 2; ++mt)
            #pragma unroll
            for (int nt = 0; nt < 2; ++nt) {
                acc[mt][nt] = __builtin_amdgcn_mfma_f32_16x16x32_bf16(
                    ah[mt], bh[nt], acc[mt][nt], 0, 0, 0);
                acc[mt][nt] = __builtin_amdgcn_mfma_f32_16x16x32_bf16(
                    ah[mt], bl[nt], acc[mt][nt], 0, 0, 0);
                acc[mt][nt] = __builtin_amdgcn_mfma_f32_16x16x32_bf16(
                    al[mt], bh[nt], acc[mt][nt], 0, 0, 0);
            }
    }

    // Epilogue. C/D: col = lane&15, row = quad*4 + reg  [m89-verified]
    #pragma unroll
    for (int nt = 0; nt < 2; ++nt) {
        int col = n0 + wn * 32 + nt * 16 + l15;
        float bv = biasAll[col];
        #pragma unroll
        for (int mt = 0; mt < 2; ++mt) {
            int row0 = m0 + wm * 32 + mt * 16 + quad * 4;
            #pragma unroll
            for (int r = 0; r < 4; ++r)
                Y[(size_t)(row0 + r) * NCOLS + col] = acc[mt][nt][r] + bv;
        }
    }
}

// ---------------------------------------------------------------------------
// Stage 2: fused branches (UNCHANGED). One wave per row; moments in
// registers, LDS-transpose reduce, Horner per i.
// ---------------------------------------------------------------------------
#define PSTR 53

__global__ __launch_bounds__(64) void fused_attn(const float* __restrict__ Y,
                                                 float* __restrict__ out) {
    const int row = blockIdx.x;
    const int l   = threadIdx.x;
    const float* __restrict__ Yr = Y + (size_t)row * NCOLS;
    const int i0 = l * 8;

    __shared__ float part[64 * PSTR];
    __shared__ float cbuf[50];

    const float LOG2E = 1.4426950408889634f;

    float4 qf0 = *(const float4*)(Yr + i0);
    float4 qf1 = *(const float4*)(Yr + i0 + 4);
    float4 kf0 = *(const float4*)(Yr + 512 + i0);
    float4 kf1 = *(const float4*)(Yr + 512 + i0 + 4);
    float4 vf0 = *(const float4*)(Yr + 1024 + i0);
    float4 vf1 = *(const float4*)(Yr + 1024 + i0 + 4);
    float4 qt0 = *(const float4*)(Yr + 1536 + i0);
    float4 qt1 = *(const float4*)(Yr + 1536 + i0 + 4);
    float4 kt0 = *(const float4*)(Yr + 2048 + i0);
    float4 kt1 = *(const float4*)(Yr + 2048 + i0 + 4);
    float4 vt0 = *(const float4*)(Yr + 2560 + i0);
    float4 vt1 = *(const float4*)(Yr + 2560 + i0 + 4);

    float e[8];
    e[0] = __builtin_amdgcn_exp2f(qf0.x * kf0.x * LOG2E);
    e[1] = __builtin_amdgcn_exp2f(qf0.y * kf0.y * LOG2E);
    e[2] = __builtin_amdgcn_exp2f(qf0.z * kf0.z * LOG2E);
    e[3] = __builtin_amdgcn_exp2f(qf0.w * kf0.w * LOG2E);
    e[4] = __builtin_amdgcn_exp2f(qf1.x * kf1.x * LOG2E);
    e[5] = __builtin_amdgcn_exp2f(qf1.y * kf1.y * LOG2E);
    e[6] = __builtin_amdgcn_exp2f(qf1.z * kf1.z * LOG2E);
    e[7] = __builtin_amdgcn_exp2f(qf1.w * kf1.w * LOG2E);
    float psum = ((e[0] + e[1]) + (e[2] + e[3])) + ((e[4] + e[5]) + (e[6] + e[7]));
    #pragma unroll
    for (int off = 32; off; off >>= 1) psum += __shfl_xor(psum, off);
    const float invS = 1.0f / psum;

    float k[8] = {kt0.x, kt0.y, kt0.z, kt0.w, kt1.x, kt1.y, kt1.z, kt1.w};
    float v[8] = {vt0.x, vt0.y, vt0.z, vt0.w, vt1.x, vt1.y, vt1.z, vt1.w};
    float kp[8] = {1.f, 1.f, 1.f, 1.f, 1.f, 1.f, 1.f, 1.f};
    float* myrow = &part[l * PSTR];
    #pragma unroll
    for (int p = 0; p < 25; ++p) {
        float n = ((kp[0] + kp[1]) + (kp[2] + kp[3])) +
                  ((kp[4] + kp[5]) + (kp[6] + kp[7]));
        float m = fmaf(kp[7], v[7], fmaf(kp[6], v[6],
                  fmaf(kp[5], v[5], fmaf(kp[4], v[4],
                  fmaf(kp[3], v[3], fmaf(kp[2], v[2],
                  fmaf(kp[1], v[1], kp[0] * v[0])))))));
        myrow[p]      = m;
        myrow[25 + p] = n;
        #pragma unroll
        for (int j = 0; j < 8; ++j) kp[j] *= k[j];
    }
    __syncthreads();

    if (l < 50) {
        float s = 0.f;
        #pragma unroll
        for (int i = 0; i < 64; ++i) s += part[i * PSTR + l];
        cbuf[l] = s * INVFACT[l < 25 ? l : l - 25];
    }
    __syncthreads();

    float q[8] = {qt0.x, qt0.y, qt0.z, qt0.w, qt1.x, qt1.y, qt1.z, qt1.w};
    float F[8], G[8];
    {
        float cf = cbuf[24], cg = cbuf[49];
        #pragma unroll
        for (int c = 0; c < 8; ++c) { F[c] = cf; G[c] = cg; }
    }
    #pragma unroll
    for (int p = 23; p >= 0; --p) {
        float cf = cbuf[p], cg = cbuf[25 + p];
        #pragma unroll
        for (int c = 0; c < 8; ++c) {
            F[c] = fmaf(F[c], q[c], cf);
            G[c] = fmaf(G[c], q[c], cg);
        }
    }

    float4 o0, o1;
    o0.x = e[0] * invS * vf0.x + F[0] / G[0];
    o0.y = e[1] * invS * vf0.y + F[1] / G[1];
    o0.z = e[2] * invS * vf0.z + F[2] / G[2];
    o0.w = e[3] * invS * vf0.w + F[3] / G[3];
    o1.x = e[4] * invS * vf1.x + F[4] / G[4];
    o1.y = e[5] * invS * vf1.y + F[5] / G[5];
    o1.z = e[6] * invS * vf1.z + F[6] / G[6];
    o1.w = e[7] * invS * vf1.w + F[7] / G[7];
    *(float4*)(out + (size_t)row * DIMD + i0)     = o0;
    *(float4*)(out + (size_t)row * DIMD + i0 + 4) = o1;
}

extern "C" void kernel_launch(void* const* d_in, const int* in_sizes, int n_in,
                              void* d_out, int out_size, void* d_ws, size_t ws_size,
                              hipStream_t stream) {
    const float* x = (const float*)d_in[0];
    PtrArgs pa;
    for (int g = 0; g < 6; ++g) {
        pa.W[g] = (const float*)d_in[1 + 2 * g];
        pa.b[g] = (const float*)d_in[2 + 2 * g];
    }

    // Workspace layout:
    //   Y:    [1024][3072] fp32  = 12,582,912 B
    //   Aph:  [1024][1024] bf16  =  2,097,152 B
    //   Bph:  [3072][1024] bf16  =  6,291,456 B
    //   bias: [3072] fp32        =     12,288 B
    char* ws = (char*)d_ws;
    float*          Y    = (float*)ws;
    unsigned short* Aph  = (unsigned short*)(ws + 12582912);
    unsigned short* Bph  = (unsigned short*)(ws + 12582912 + 2097152);
    float*          bias = (float*)(ws + 12582912 + 2097152 + 6291456);

    convert_split<<<(XN + WN) / 4 / 256, 256, 0, stream>>>(x, pa, Aph, Bph, bias);

    dim3 g1(NCOLS / 64, M_ROWS / 64);   // 48 x 16 = 768 blocks
    gemm_mfma<<<g1, 256, 0, stream>>>(Aph, Bph, bias, Y);

    fused_attn<<<M_ROWS, 64, 0, stream>>>(Y, (float*)d_out);
}